// Round 10
// baseline (616.377 us; speedup 1.0000x reference)
//
#include <hip/hip_runtime.h>

// CentroidPool: N=65536 x K=4096 x D=128 fp32 -> argmin_k ||x - c_k|| (int32).
// Stage 1: f16x3-split MFMA GEMM (xh*ch + xh*cl + xl*ch, fp32 acc = c2 init),
//   top-2 tracked via sortable packed keys (score bits | tile id), 4 VALU
//   ops/slot. B-stream software-pipelined: register ping-pong, loads for
//   step s+1 issued before step s's MFMAs. ROUND-9 BUG FIXED: the tile-advance
//   (+32*128-96) must precede the 4th prefetch so it lands on (kt+1, ds=0);
//   round 9 applied it after -> 4th pfB read centroid k0+1 -> absmax 4096.
// Stage 2: exact fp64 rescore of the 2 candidates (near-tie rescue).

typedef _Float16 f16;
typedef f16  f16x8 __attribute__((ext_vector_type(8)));
typedef float f32x4 __attribute__((ext_vector_type(4)));

constexpr int N_PTS  = 65536;
constexpr int K_CENT = 4096;
constexpr int D_DIM  = 128;
constexpr int MB     = 64;     // points per block (4 waves share them)
constexpr int KW     = 1024;   // centroids per wave (waves split K 4-ways)
constexpr float SOFF = 256.0f; // score offset => strictly positive scores

// ---------------------------------------------------------------------------
__global__ __launch_bounds__(256) void c2_kernel(const float* __restrict__ coords,
                                                 float* __restrict__ c2b) {
    int k = blockIdx.x * 256 + threadIdx.x;
    const float* c = coords + (size_t)k * D_DIM;
    float s = 0.f;
#pragma unroll
    for (int d = 0; d < D_DIM; ++d) s = fmaf(c[d], c[d], s);
    c2b[k] = s + SOFF;
}

__global__ __launch_bounds__(256) void split_coords(const float* __restrict__ c,
                                                    f16* __restrict__ ch,
                                                    f16* __restrict__ cl) {
    int e = blockIdx.x * 256 + threadIdx.x;
    float x = c[e];
    f16 h = (f16)x;
    ch[e] = h;
    cl[e] = (f16)(x - (float)h);
}

// ---------------------------------------------------------------------------
// Stage 1. Block = 4 waves x 64 points; latent (-2x) split h/l in XOR-swizzled
// LDS (stride 128 f16, 16-B unit col8 ^= row&15 -> conflict-free reads).
// Wave w scans cents [w*1024,(w+1)*1024) in 32-wide k-tiles (2 n-groups),
// ds-steps pipelined via register ping-pong. key = (bits(score)&~63)|kn,
// kn = kt*2+n (6b); top-2 = u32 min/max chain; cent = (wave*64+kn)*16 + l15.
// ---------------------------------------------------------------------------
__global__ __launch_bounds__(256, 3) void argmin_mfma(
        const float* __restrict__ latent,
        const f16*   __restrict__ ch,
        const f16*   __restrict__ cl,
        const float* __restrict__ c2b,
        int* __restrict__ top1,
        int* __restrict__ top2) {
    __shared__ f16 latH[MB * 128];
    __shared__ f16 latL[MB * 128];
    __shared__ unsigned r1K[4][MB]; __shared__ int r1I[4][MB];
    __shared__ unsigned r2K[4][MB]; __shared__ int r2I[4][MB];

    const int t    = threadIdx.x;
    const int wave = t >> 6;
    const int lane = t & 63;
    const int quad = lane >> 4;
    const int l15  = lane & 15;
    const int row0 = blockIdx.x * MB;

    {   // Stage latent: scale -2, split h/l, XOR-swizzle 16-B units.
        const float4* src = (const float4*)(latent + (size_t)row0 * D_DIM);
#pragma unroll
        for (int i = 0; i < 4; ++i) {
            int g  = i * 256 + t;          // float8 index in [0,1024)
            int r  = g >> 4;               // row (16 float8 per row)
            int c8 = g & 15;               // logical 16-B column
            float4 v0 = src[2 * g];
            float4 v1 = src[2 * g + 1];
            float xs[8] = {v0.x, v0.y, v0.z, v0.w, v1.x, v1.y, v1.z, v1.w};
            f16x8 hv, lv;
#pragma unroll
            for (int c = 0; c < 8; ++c) {
                float x = -2.0f * xs[c];
                f16 h = (f16)x;
                hv[c] = h;
                lv[c] = (f16)(x - (float)h);
            }
            int pc = ((c8 ^ (r & 15)) << 3);
            *(f16x8*)&latH[r * 128 + pc] = hv;
            *(f16x8*)&latL[r * 128 + pc] = lv;
        }
    }
    __syncthreads();

    unsigned b1[16], b2[16];
#pragma unroll
    for (int i = 0; i < 16; ++i) { b1[i] = 0xFFFFFFFFu; b2[i] = 0xFFFFFFFFu; }

    const int wbase = wave * KW;
    // offB = element offset of the next B load (n-group 0); n-group 1 = +2048.
    // Invariant at tile top: Ba holds (kt, ds0), offB -> (kt, ds1).
    unsigned offB = (unsigned)(wbase + l15) * 128u + (unsigned)(quad * 8);

    f16x8 Ba[4], Bb[4];
    auto pfB = [&](f16x8* Bv) {
        Bv[0] = *(const f16x8*)(ch + offB);
        Bv[1] = *(const f16x8*)(cl + offB);
        Bv[2] = *(const f16x8*)(ch + offB + 2048);
        Bv[3] = *(const f16x8*)(cl + offB + 2048);
    };

    f32x4 acc[8];
    auto step = [&](const f16x8* Bv, int ds) {
        f16x8 ah[4], al[4];
        const int pc = (((ds << 2) + quad) ^ l15) << 3;
#pragma unroll
        for (int m = 0; m < 4; ++m) {
            ah[m] = *(const f16x8*)&latH[(m * 16 + l15) * 128 + pc];
            al[m] = *(const f16x8*)&latL[(m * 16 + l15) * 128 + pc];
        }
#pragma unroll
        for (int m = 0; m < 4; ++m)
#pragma unroll
            for (int n = 0; n < 2; ++n) {
                f32x4 a = acc[m * 2 + n];
                a = __builtin_amdgcn_mfma_f32_16x16x32_f16(ah[m], Bv[2 * n],     a, 0, 0, 0);
                a = __builtin_amdgcn_mfma_f32_16x16x32_f16(ah[m], Bv[2 * n + 1], a, 0, 0, 0);
                a = __builtin_amdgcn_mfma_f32_16x16x32_f16(al[m], Bv[2 * n],     a, 0, 0, 0);
                acc[m * 2 + n] = a;
            }
    };

    // Prime: load (kt=0, ds=0) into Ba; offB -> (0, ds1).
    pfB(Ba);
    offB += 32;
    float cv0 = c2b[wbase + l15];
    float cv1 = c2b[wbase + 16 + l15];

#pragma unroll 1
    for (int kt = 0; kt < KW / 32; ++kt) {
        // acc init = c2 (saves the epilogue add).
#pragma unroll
        for (int m = 0; m < 4; ++m) {
            acc[m * 2 + 0] = (f32x4){cv0, cv0, cv0, cv0};
            acc[m * 2 + 1] = (f32x4){cv1, cv1, cv1, cv1};
        }
        // Prefetch next tile's c2 (wraps at the end; value then unused).
        int ktn = (kt + 1) & 31;
        float cvn0 = c2b[wbase + ktn * 32 + l15];
        float cvn1 = c2b[wbase + ktn * 32 + 16 + l15];

        pfB(Bb); offB += 32;             step(Ba, 0);  // loads (kt,ds1) -> (kt,ds2)
        pfB(Ba); offB += 32;             step(Bb, 1);  // loads (kt,ds2) -> (kt,ds3)
        pfB(Bb); offB += 32 * 128 - 96;  step(Ba, 2);  // loads (kt,ds3) -> (kt+1,ds0)
        if (kt != KW / 32 - 1) pfB(Ba);                // loads (kt+1,ds0)
        offB += 32;                                    // -> (kt+1,ds1)
        step(Bb, 3);

        // Epilogue: 4 VALU ops per slot (and_or, max, min, min).
#pragma unroll
        for (int n = 0; n < 2; ++n) {
            const unsigned kn = (unsigned)(kt * 2 + n);
#pragma unroll
            for (int m = 0; m < 4; ++m) {
                f32x4 a = acc[m * 2 + n];
#pragma unroll
                for (int r = 0; r < 4; ++r) {
                    unsigned key = (__float_as_uint(a[r]) & 0xFFFFFFC0u) | kn;
                    unsigned hi = key > b1[m * 4 + r] ? key : b1[m * 4 + r];
                    b1[m * 4 + r] = key < b1[m * 4 + r] ? key : b1[m * 4 + r];
                    b2[m * 4 + r] = hi  < b2[m * 4 + r] ? hi  : b2[m * 4 + r];
                }
            }
        }
        cv0 = cvn0; cv1 = cvn1;
    }

    // Quad butterfly: merge two sorted-2 (key,idx) lists per step.
#pragma unroll
    for (int m = 0; m < 4; ++m)
#pragma unroll
        for (int r = 0; r < 4; ++r) {
            unsigned k1 = b1[m * 4 + r], k2 = b2[m * 4 + r];
            int i1 = ((wave * 64 + (int)(k1 & 63u)) << 4) | l15;
            int i2 = ((wave * 64 + (int)(k2 & 63u)) << 4) | l15;
#pragma unroll
            for (int msk = 1; msk < 16; msk <<= 1) {
                unsigned ok1 = (unsigned)__shfl_xor((int)k1, msk, 64);
                int      oi1 = __shfl_xor(i1, msk, 64);
                unsigned ok2 = (unsigned)__shfl_xor((int)k2, msk, 64);
                int      oi2 = __shfl_xor(i2, msk, 64);
                bool ow = ok1 < k1;
                unsigned w1k = ow ? ok1 : k1; int w1i = ow ? oi1 : i1;
                unsigned lsk = ow ? k1 : ok1; int lsi = ow ? i1 : oi1;
                unsigned wsk = ow ? ok2 : k2; int wsi = ow ? oi2 : i2;
                bool sw = lsk < wsk;
                k1 = w1k; i1 = w1i;
                k2 = sw ? lsk : wsk; i2 = sw ? lsi : wsi;
            }
            if (l15 == 0) {
                int p = m * 16 + quad * 4 + r;
                r1K[wave][p] = k1; r1I[wave][p] = i1;
                r2K[wave][p] = k2; r2I[wave][p] = i2;
            }
        }
    __syncthreads();

    if (t < MB) {
        unsigned k1 = r1K[0][t], k2 = r2K[0][t];
        int      i1 = r1I[0][t], i2 = r2I[0][t];
#pragma unroll
        for (int w = 1; w < 4; ++w) {
            unsigned ok1 = r1K[w][t], ok2 = r2K[w][t];
            int      oi1 = r1I[w][t], oi2 = r2I[w][t];
            bool ow = ok1 < k1;
            unsigned w1k = ow ? ok1 : k1; int w1i = ow ? oi1 : i1;
            unsigned lsk = ow ? k1 : ok1; int lsi = ow ? i1 : oi1;
            unsigned wsk = ow ? ok2 : k2; int wsi = ow ? oi2 : i2;
            bool sw = lsk < wsk;
            k1 = w1k; i1 = w1i;
            k2 = sw ? lsk : wsk; i2 = sw ? lsi : wsi;
        }
        top1[row0 + t] = i1;
        top2[row0 + t] = i2;
    }
}

// ---------------------------------------------------------------------------
// Stage 2: exact fp64 rescore of the two candidates; true winner wins
// (idx tie -> smaller index).
// ---------------------------------------------------------------------------
__global__ __launch_bounds__(256) void rescore(const float* __restrict__ latent,
                                               const float* __restrict__ coords,
                                               const int* __restrict__ top1,
                                               const int* __restrict__ top2,
                                               int* __restrict__ out) {
    int n = blockIdx.x * 256 + threadIdx.x;
    int i1 = top1[n], i2 = top2[n];
    const float* x  = latent + (size_t)n * D_DIM;
    const float* ca = coords + (size_t)i1 * D_DIM;
    const float* cb = coords + (size_t)i2 * D_DIM;
    double d1 = 0.0, d2 = 0.0;
#pragma unroll
    for (int d = 0; d < D_DIM; d += 4) {
        float4 xv = *(const float4*)(x + d);
        float4 av = *(const float4*)(ca + d);
        float4 bv = *(const float4*)(cb + d);
        double e;
        e = (double)xv.x - (double)av.x; d1 += e * e;
        e = (double)xv.y - (double)av.y; d1 += e * e;
        e = (double)xv.z - (double)av.z; d1 += e * e;
        e = (double)xv.w - (double)av.w; d1 += e * e;
        e = (double)xv.x - (double)bv.x; d2 += e * e;
        e = (double)xv.y - (double)bv.y; d2 += e * e;
        e = (double)xv.z - (double)bv.z; d2 += e * e;
        e = (double)xv.w - (double)bv.w; d2 += e * e;
    }
    bool second = (d2 < d1) || (d2 == d1 && i2 < i1);
    out[n] = second ? i2 : i1;
}

// ---------------------------------------------------------------------------
extern "C" void kernel_launch(void* const* d_in, const int* in_sizes, int n_in,
                              void* d_out, int out_size, void* d_ws, size_t ws_size,
                              hipStream_t stream) {
    const float* latent = (const float*)d_in[0];
    const float* coords = (const float*)d_in[1];
    int* out = (int*)d_out;

    // ws: ch [K*D] f16 | cl [K*D] f16 | c2b [K] f32 | top1 [N] | top2 [N]
    f16*   ch  = (f16*)d_ws;
    f16*   cl  = ch + (size_t)K_CENT * D_DIM;
    float* c2b = (float*)(cl + (size_t)K_CENT * D_DIM);
    int*   t1  = (int*)(c2b + K_CENT);
    int*   t2  = t1 + N_PTS;

    c2_kernel<<<dim3(K_CENT / 256), dim3(256), 0, stream>>>(coords, c2b);
    split_coords<<<dim3(K_CENT * D_DIM / 256), dim3(256), 0, stream>>>(coords, ch, cl);
    argmin_mfma<<<dim3(N_PTS / MB), dim3(256), 0, stream>>>(latent, ch, cl, c2b, t1, t2);
    rescore<<<dim3(N_PTS / 256), dim3(256), 0, stream>>>(latent, coords, t1, t2, out);
}